// Round 7
// baseline (148.650 us; speedup 1.0000x reference)
//
#include <hip/hip_runtime.h>

#define EMBD 264        // L1(256) + 8 psqt
#define NROWS 20481     // HALFKP+1
#define NR4   5121      // ceil(NROWS/4)
#define QS 5080.0f      // int8 scale: 127/0.025
#define INVQS (1.0f/5080.0f)

typedef short short8 __attribute__((ext_vector_type(8)));
typedef float f32x4  __attribute__((ext_vector_type(4)));

__device__ __forceinline__ float clamp01(float x) { return fminf(fmaxf(x, 0.f), 1.f); }
__device__ __forceinline__ unsigned short f2bf(float f) {
    unsigned u = __float_as_uint(f);
    u += 0x7fffu + ((u >> 16) & 1u);   // RNE
    return (unsigned short)(u >> 16);
}

// Merged prep: blocks [0, NR4) quantize emb -> emb8/psqt; blocks [NR4, NR4+256)
// build w1b (folded bf16 MFMA B-frags), b1c, w2p.
__global__ void prep_all(const float* __restrict__ emb, unsigned int* __restrict__ emb8,
                         float* __restrict__ psqt,
                         const float* __restrict__ w1, const float* __restrict__ fw1,
                         const float* __restrict__ b1, const float* __restrict__ fb1,
                         const float* __restrict__ w2,
                         unsigned short* __restrict__ w1b, float* __restrict__ b1c,
                         float* __restrict__ w2p) {
    if (blockIdx.x < NR4) {
        const int r = blockIdx.x * 4 + (threadIdx.x >> 6);
        const int t = threadIdx.x & 63;
        if (r >= NROWS) return;
        const bool pad = (r == NROWS - 1);
        const float4 v = *((const float4*)(emb + (size_t)r * EMBD) + t);
        int q0 = pad ? 128 : (int)rintf(v.x * QS) + 128;
        int q1 = pad ? 128 : (int)rintf(v.y * QS) + 128;
        int q2 = pad ? 128 : (int)rintf(v.z * QS) + 128;
        int q3 = pad ? 128 : (int)rintf(v.w * QS) + 128;
        q0 = min(max(q0, 0), 255); q1 = min(max(q1, 0), 255);
        q2 = min(max(q2, 0), 255); q3 = min(max(q3, 0), 255);
        emb8[(size_t)r * 64 + t] = (unsigned)q0 | ((unsigned)q1 << 8) |
                                   ((unsigned)q2 << 16) | ((unsigned)q3 << 24);
        if (t < 8) {
            float pv = emb[(size_t)r * EMBD + 256 + t];
            psqt[r * 8 + t] = pad ? 0.f : pv;
        }
    } else {
        const int e = (blockIdx.x - NR4) * 256 + threadIdx.x;   // 0..65535
        const int bkt = e >> 13, rem = e & 8191;
        const int s = rem >> 10, rem2 = rem & 1023;
        const int nt = rem2 >> 9, rem3 = rem2 & 511;
        const int ln = rem3 >> 3, j = rem3 & 7;
        const int n  = nt * 16 + (ln & 15);
        const int hi = ln >> 4;
        const int k  = s * 32 + hi * 8 + j;
        const float v = w1[(bkt * 32 + n) * 256 + k] + fw1[n * 256 + k];
        w1b[e] = f2bf(v);
        if (e < 256) b1c[e] = b1[e] + fb1[e & 31];
        if (e < 16384) {
            const int jr = e >> 6, i = e & 63;
            float x = 0.f;
            if (i < 31) x = w2[jr * 62 + i];
            else if (i >= 32 && i < 63) x = w2[jr * 62 + i - 1];
            w2p[e] = x;
        }
    }
}

__global__ __launch_bounds__(256) void nnue_fwd_mfma(
    const unsigned int* __restrict__ emb8,    // (NROWS,64) dwords, biased u8
    const float* __restrict__ psqt,           // (NROWS,8) fp32
    const unsigned short* __restrict__ w1b,   // MFMA B frags, bf16
    const float* __restrict__ b1c,            // folded (256,)
    const float* __restrict__ w2p,            // padded (256,64)
    const float* __restrict__ b2,
    const float* __restrict__ wo,
    const float* __restrict__ bo,
    const float* __restrict__ us,
    const float* __restrict__ them,
    const int*   __restrict__ w_idx,
    const int*   __restrict__ b_idx,
    const int*   __restrict__ pcnt,
    float* __restrict__ out,
    int B)
{
    // 8 batch rows per block; A rows 8..15 of the MFMA tile are never written
    // (their C rows are discarded).
    __shared__ unsigned short A_lds[16 * 280];          // 8960 B
    __shared__ float l1c[8 * 8 * 36];                   // 9216 B: [bucket][row][36-padded]
    __shared__ float psq_lds[8];
    __shared__ int   bkt_lds[8];

    const int tid  = threadIdx.x;
    const int lane = tid & 63;
    const int w    = tid >> 6;

    // ---------- phase 1: gather, 2 rows per wave ----------
    for (int rr = 0; rr < 2; ++rr) {
        const int m = w * 2 + rr;
        const int grow = blockIdx.x * 8 + m;   // B % 8 == 0

        const float usv = us[grow];
        const float thv = them[grow];
        int bucket = (pcnt[grow] - 1) >> 2;
        bucket = bucket > 7 ? 7 : bucket;
        bucket = __builtin_amdgcn_readfirstlane(bucket);

        // One coalesced load: lanes 0..31 w-side indices, 32..63 b-side.
        const int kk = lane & 31;
        const int idxv = (lane < 32) ? w_idx[grow * 32 + kk] : b_idx[grow * 32 + kk];

        // psqt side-table gather (reuses idxv layout)
        float ps = psqt[idxv * 8 + bucket];
        ps += __shfl_xor(ps, 16);
        ps += __shfl_xor(ps, 8);
        ps += __shfl_xor(ps, 4);
        ps += __shfl_xor(ps, 2);
        ps += __shfl_xor(ps, 1);
        const float psq_w = __shfl(ps, 0);
        const float psq_b = __shfl(ps, 32);

        // Gather: k-th feature row index extracted via v_readlane (imm lane).
        // k 0..31 = w side, 32..63 = b side. Packed-u16 exact accumulation.
        unsigned aw0 = 0, aw1 = 0, ab0 = 0, ab1 = 0;
        const unsigned M = 0x00FF00FFu;
#pragma unroll
        for (int kb = 0; kb < 64; kb += 16) {
            unsigned v[16];
#pragma unroll
            for (int k2 = 0; k2 < 16; ++k2) {
                const int idx = __builtin_amdgcn_readlane(idxv, kb + k2);
                v[k2] = emb8[(size_t)idx * 64 + lane];
            }
#pragma unroll
            for (int k2 = 0; k2 < 16; ++k2) {
                if (kb + k2 < 32) { aw0 += v[k2] & M; aw1 += (v[k2] >> 8) & M; }
                else              { ab0 += v[k2] & M; ab1 += (v[k2] >> 8) & M; }
            }
        }
        float4 aw, ab;
        aw.x = ((int)(aw0 & 0xffffu) - 4096) * INVQS;
        aw.y = ((int)(aw1 & 0xffffu) - 4096) * INVQS;
        aw.z = ((int)(aw0 >> 16)     - 4096) * INVQS;
        aw.w = ((int)(aw1 >> 16)     - 4096) * INVQS;
        ab.x = ((int)(ab0 & 0xffffu) - 4096) * INVQS;
        ab.y = ((int)(ab1 & 0xffffu) - 4096) * INVQS;
        ab.z = ((int)(ab0 >> 16)     - 4096) * INVQS;
        ab.w = ((int)(ab1 >> 16)     - 4096) * INVQS;

        float4 p, q;
        p.x = clamp01(usv * aw.x + thv * ab.x);
        p.y = clamp01(usv * aw.y + thv * ab.y);
        p.z = clamp01(usv * aw.z + thv * ab.z);
        p.w = clamp01(usv * aw.w + thv * ab.w);
        q.x = clamp01(usv * ab.x + thv * aw.x);
        q.y = clamp01(usv * ab.y + thv * aw.y);
        q.z = clamp01(usv * ab.z + thv * aw.z);
        q.w = clamp01(usv * ab.w + thv * aw.w);

        float4 po, qo;
        po.x = __shfl_xor(p.x, 32); po.y = __shfl_xor(p.y, 32);
        po.z = __shfl_xor(p.z, 32); po.w = __shfl_xor(p.w, 32);
        qo.x = __shfl_xor(q.x, 32); qo.y = __shfl_xor(q.y, 32);
        qo.z = __shfl_xor(q.z, 32); qo.w = __shfl_xor(q.w, 32);
        const float c127 = 127.f / 128.f;
        float4 l0f;
        if (lane < 32) {
            l0f.x = p.x * po.x * c127; l0f.y = p.y * po.y * c127;
            l0f.z = p.z * po.z * c127; l0f.w = p.w * po.w * c127;
        } else {
            l0f.x = q.x * qo.x * c127; l0f.y = q.y * qo.y * c127;
            l0f.z = q.z * qo.z * c127; l0f.w = q.w * qo.w * c127;
        }

        const unsigned lo  = (unsigned)f2bf(l0f.x) | ((unsigned)f2bf(l0f.y) << 16);
        const unsigned hi2 = (unsigned)f2bf(l0f.z) | ((unsigned)f2bf(l0f.w) << 16);
        *((unsigned long long*)&A_lds[m * 280 + lane * 4]) =
            ((unsigned long long)hi2 << 32) | (unsigned long long)lo;
        if (lane == 0) {
            psq_lds[m] = (psq_w - psq_b) * (usv - 0.5f);
            bkt_lds[m] = bucket;
        }
    }
    __syncthreads();

    // ---------- phase 2: l1 via MFMA for all 8 buckets (2 per wave) ----------
    {
        const int col = lane & 15;
        const int hi  = lane >> 4;
        f32x4 acc[2][2];
#pragma unroll
        for (int bb = 0; bb < 2; ++bb)
#pragma unroll
            for (int nt = 0; nt < 2; ++nt)
                acc[bb][nt] = (f32x4){0.f, 0.f, 0.f, 0.f};

#pragma unroll
        for (int s = 0; s < 8; ++s) {
            const short8 a = *((const short8*)&A_lds[col * 280 + s * 32 + hi * 8]);
#pragma unroll
            for (int bb = 0; bb < 2; ++bb) {
                const int bkt = w * 2 + bb;
#pragma unroll
                for (int nt = 0; nt < 2; ++nt) {
                    const short8 bf = *((const short8*)&w1b[(((bkt * 8 + s) * 2 + nt) * 64 + lane) * 8]);
                    acc[bb][nt] = __builtin_amdgcn_mfma_f32_16x16x32_bf16(a, bf, acc[bb][nt], 0, 0, 0);
                }
            }
        }
        // Only C rows 0..7 are valid batch rows (hi<2).
        if (hi < 2) {
#pragma unroll
            for (int bb = 0; bb < 2; ++bb) {
                const int bkt = w * 2 + bb;
#pragma unroll
                for (int nt = 0; nt < 2; ++nt) {
                    const float bias = b1c[bkt * 32 + nt * 16 + col];
#pragma unroll
                    for (int reg = 0; reg < 4; ++reg) {
                        const int mr = hi * 4 + reg;
                        l1c[(bkt * 8 + mr) * 36 + nt * 16 + col] = acc[bb][nt][reg] + bias;
                    }
                }
            }
        }
    }
    __syncthreads();

    // ---------- phase 3: l2 + l3, thread = (row, output-pair), tid < 128 ----------
    if (tid < 128) {
        const int row = tid >> 4;
        const int jj  = tid & 15;
        const int bkt = bkt_lds[row];
        const float4* crow = (const float4*)&l1c[(bkt * 8 + row) * 36];
        float4 c4[8];
#pragma unroll
        for (int b5 = 0; b5 < 8; ++b5) c4[b5] = crow[b5];

        const float4* wr0 = (const float4*)&w2p[(bkt * 32 + jj) * 64];
        const float4* wr1 = (const float4*)&w2p[(bkt * 32 + jj + 16) * 64];
        float acc0 = 0.f, acc1 = 0.f;
        const float kq = 255.f / 256.f;
#pragma unroll
        for (int b5 = 0; b5 < 8; ++b5) {
            const float4 cv = c4[b5];
            float4 sq, ln;
            sq.x = clamp01(cv.x * cv.x * kq); ln.x = clamp01(cv.x);
            sq.y = clamp01(cv.y * cv.y * kq); ln.y = clamp01(cv.y);
            sq.z = clamp01(cv.z * cv.z * kq); ln.z = clamp01(cv.z);
            sq.w = clamp01(cv.w * cv.w * kq); ln.w = clamp01(cv.w);
            const float4 ws0 = wr0[b5], wl0 = wr0[8 + b5];
            const float4 ws1 = wr1[b5], wl1 = wr1[8 + b5];
            acc0 += sq.x * ws0.x + sq.y * ws0.y + sq.z * ws0.z + sq.w * ws0.w;
            acc0 += ln.x * wl0.x + ln.y * wl0.y + ln.z * wl0.z + ln.w * wl0.w;
            acc1 += sq.x * ws1.x + sq.y * ws1.y + sq.z * ws1.z + sq.w * ws1.w;
            acc1 += ln.x * wl1.x + ln.y * wl1.y + ln.z * wl1.z + ln.w * wl1.w;
        }
        const float t0 = clamp01(acc0 + b2[bkt * 32 + jj])      * wo[bkt * 32 + jj];
        const float t1 = clamp01(acc1 + b2[bkt * 32 + jj + 16]) * wo[bkt * 32 + jj + 16];
        float t = t0 + t1;
        t += __shfl_xor(t, 8);
        t += __shfl_xor(t, 4);
        t += __shfl_xor(t, 2);
        t += __shfl_xor(t, 1);
        if (jj == 0) {
            out[blockIdx.x * 8 + row] = t + bo[bkt] + c4[7].w + psq_lds[row];
        }
    }
}

// ---------- fp32 fallback (self-contained, no workspace) ----------
__global__ __launch_bounds__(256) void nnue_fwd_f32(
    const float* __restrict__ emb,
    const float* __restrict__ w1e, const float* __restrict__ fw1,
    const float* __restrict__ b1e, const float* __restrict__ fb1,
    const float* __restrict__ w2,  const float* __restrict__ b2,
    const float* __restrict__ wo,  const float* __restrict__ bo,
    const float* __restrict__ us,  const float* __restrict__ them,
    const int* __restrict__ w_idx, const int* __restrict__ b_idx,
    const int* __restrict__ pcnt,  float* __restrict__ out, int B)
{
    const int lane = threadIdx.x & 63;
    const int row  = blockIdx.x * 4 + (threadIdx.x >> 6);
    if (row >= B) return;
    const float usv = us[row];
    const float thv = them[row];
    int bucket = (pcnt[row] - 1) >> 2;
    bucket = bucket > 7 ? 7 : bucket;
    bucket = __builtin_amdgcn_readfirstlane(bucket);
    const int kk = lane & 31;
    const int myidx = (lane < 32) ? w_idx[row * 32 + kk] : b_idx[row * 32 + kk];
    float ps = emb[(size_t)myidx * EMBD + 256 + bucket];
    ps += __shfl_xor(ps, 16); ps += __shfl_xor(ps, 8);
    ps += __shfl_xor(ps, 4);  ps += __shfl_xor(ps, 2); ps += __shfl_xor(ps, 1);
    const float psq_w = __shfl(ps, 0);
    const float psq_b = __shfl(ps, 32);
    float4 aw = make_float4(0,0,0,0), ab = make_float4(0,0,0,0);
#pragma unroll
    for (int k = 0; k < 32; ++k) {
        const int iw = __shfl(myidx, k);
        const int ib = __shfl(myidx, 32 + k);
        const float4 vw = *((const float4*)(emb + (size_t)iw * EMBD) + lane);
        const float4 vb = *((const float4*)(emb + (size_t)ib * EMBD) + lane);
        aw.x += vw.x; aw.y += vw.y; aw.z += vw.z; aw.w += vw.w;
        ab.x += vb.x; ab.y += vb.y; ab.z += vb.z; ab.w += vb.w;
    }
    float4 p, q;
    p.x = clamp01(usv*aw.x + thv*ab.x); p.y = clamp01(usv*aw.y + thv*ab.y);
    p.z = clamp01(usv*aw.z + thv*ab.z); p.w = clamp01(usv*aw.w + thv*ab.w);
    q.x = clamp01(usv*ab.x + thv*aw.x); q.y = clamp01(usv*ab.y + thv*aw.y);
    q.z = clamp01(usv*ab.z + thv*aw.z); q.w = clamp01(usv*ab.w + thv*aw.w);
    float4 po, qo;
    po.x = __shfl_xor(p.x,32); po.y = __shfl_xor(p.y,32);
    po.z = __shfl_xor(p.z,32); po.w = __shfl_xor(p.w,32);
    qo.x = __shfl_xor(q.x,32); qo.y = __shfl_xor(q.y,32);
    qo.z = __shfl_xor(q.z,32); qo.w = __shfl_xor(q.w,32);
    const float c127 = 127.f/128.f;
    float4 l0f;
    if (lane < 32) { l0f.x=p.x*po.x*c127; l0f.y=p.y*po.y*c127; l0f.z=p.z*po.z*c127; l0f.w=p.w*po.w*c127; }
    else           { l0f.x=q.x*qo.x*c127; l0f.y=q.y*qo.y*c127; l0f.z=q.z*qo.z*c127; l0f.w=q.w*qo.w*c127; }
    float part[32];
    const float4* w1p = (const float4*)(w1e + (size_t)bucket * 8192);
    const float4* f1p = (const float4*)fw1;
#pragma unroll
    for (int j = 0; j < 32; ++j) {
        float4 wv = w1p[j*64 + lane];
        float4 fv = f1p[j*64 + lane];
        wv.x+=fv.x; wv.y+=fv.y; wv.z+=fv.z; wv.w+=fv.w;
        part[j] = l0f.x*wv.x + l0f.y*wv.y + l0f.z*wv.z + l0f.w*wv.w;
    }
#pragma unroll
    for (int j = 0; j < 32; ++j) {
        float v = part[j];
        v += __shfl_xor(v,32); v += __shfl_xor(v,16); v += __shfl_xor(v,8);
        v += __shfl_xor(v,4);  v += __shfl_xor(v,2);  v += __shfl_xor(v,1);
        part[j] = v + b1e[bucket*32 + j] + fb1[j];
    }
    const float l1x_out = part[31];
    float acc2 = 0.f;
    if (lane < 32) {
        const float* w2r = w2 + (size_t)(bucket*32 + lane) * 62;
#pragma unroll
        for (int i = 0; i < 31; ++i) {
            const float a = part[i];
            acc2 += clamp01(a*a*(255.f/256.f)) * w2r[i];
            acc2 += clamp01(a) * w2r[31+i];
        }
        acc2 += b2[bucket*32 + lane];
        acc2 = clamp01(acc2) * wo[bucket*32 + lane];
    }
    acc2 += __shfl_xor(acc2,16); acc2 += __shfl_xor(acc2,8);
    acc2 += __shfl_xor(acc2,4);  acc2 += __shfl_xor(acc2,2); acc2 += __shfl_xor(acc2,1);
    if (lane == 0)
        out[row] = acc2 + bo[bucket] + l1x_out + (psq_w - psq_b) * (usv - 0.5f);
}

extern "C" void kernel_launch(void* const* d_in, const int* in_sizes, int n_in,
                              void* d_out, int out_size, void* d_ws, size_t ws_size,
                              hipStream_t stream) {
    const float* emb  = (const float*)d_in[0];
    const float* w1   = (const float*)d_in[1];
    const float* b1   = (const float*)d_in[2];
    const float* fw1  = (const float*)d_in[3];
    const float* fb1  = (const float*)d_in[4];
    const float* w2   = (const float*)d_in[5];
    const float* b2   = (const float*)d_in[6];
    const float* wo   = (const float*)d_in[7];
    const float* bo   = (const float*)d_in[8];
    const float* us   = (const float*)d_in[9];
    const float* them = (const float*)d_in[10];
    const int*   wi   = (const int*)d_in[11];
    const int*   bi   = (const int*)d_in[12];
    const int*   pc   = (const int*)d_in[13];
    float* out = (float*)d_out;

    const int B = in_sizes[9];               // 16384

    const size_t emb8_bytes = (size_t)NROWS * 256;   // 5,243,136
    const size_t psqt_bytes = (size_t)NROWS * 8 * 4; //   655,392
    const size_t w1b_bytes  = 65536 * 2;
    const size_t b1c_bytes  = 256 * 4;
    const size_t w2p_bytes  = 16384 * 4;
    const size_t need = emb8_bytes + psqt_bytes + w1b_bytes + b1c_bytes + w2p_bytes;

    if (ws_size >= need && (B % 8) == 0) {
        char* p = (char*)d_ws;
        unsigned int*   emb8 = (unsigned int*)p;     p += emb8_bytes;
        float*          psqt = (float*)p;            p += psqt_bytes;
        unsigned short* w1b  = (unsigned short*)p;   p += w1b_bytes;
        float*          b1c  = (float*)p;            p += b1c_bytes;
        float*          w2p  = (float*)p;

        prep_all<<<NR4 + 256, 256, 0, stream>>>(emb, emb8, psqt,
                                                w1, fw1, b1, fb1, w2, w1b, b1c, w2p);
        nnue_fwd_mfma<<<B / 8, 256, 0, stream>>>(emb8, psqt, w1b, b1c, w2p,
                                                 b2, wo, bo, us, them, wi, bi, pc, out, B);
    } else {
        nnue_fwd_f32<<<(B + 3) / 4, 256, 0, stream>>>(emb, w1, fw1, b1, fb1,
                                                      w2, b2, wo, bo, us, them, wi, bi, pc, out, B);
    }
}

// Round 8
// 143.139 us; speedup vs baseline: 1.0385x; 1.0385x over previous
//
#include <hip/hip_runtime.h>

#define EMBD 264        // L1(256) + 8 psqt
#define NROWS 20481     // HALFKP+1
#define NR4   5121      // ceil(NROWS/4)
#define QS 5080.0f      // int8 scale: 127/0.025
#define INVQS (1.0f/5080.0f)

typedef short short8 __attribute__((ext_vector_type(8)));
typedef float f32x4  __attribute__((ext_vector_type(4)));

__device__ __forceinline__ float clamp01(float x) { return fminf(fmaxf(x, 0.f), 1.f); }
__device__ __forceinline__ unsigned short f2bf(float f) {
    unsigned u = __float_as_uint(f);
    u += 0x7fffu + ((u >> 16) & 1u);   // RNE
    return (unsigned short)(u >> 16);
}

// Merged prep: blocks [0, NR4) quantize emb -> emb8/psqt; blocks [NR4, NR4+256)
// build w1b (folded bf16 MFMA B-frags), b1c, w2p.
__global__ void prep_all(const float* __restrict__ emb, unsigned int* __restrict__ emb8,
                         float* __restrict__ psqt,
                         const float* __restrict__ w1, const float* __restrict__ fw1,
                         const float* __restrict__ b1, const float* __restrict__ fb1,
                         const float* __restrict__ w2,
                         unsigned short* __restrict__ w1b, float* __restrict__ b1c,
                         float* __restrict__ w2p) {
    if (blockIdx.x < NR4) {
        const int r = blockIdx.x * 4 + (threadIdx.x >> 6);
        const int t = threadIdx.x & 63;
        if (r >= NROWS) return;
        const bool pad = (r == NROWS - 1);
        const float4 v = *((const float4*)(emb + (size_t)r * EMBD) + t);
        int q0 = pad ? 128 : (int)rintf(v.x * QS) + 128;
        int q1 = pad ? 128 : (int)rintf(v.y * QS) + 128;
        int q2 = pad ? 128 : (int)rintf(v.z * QS) + 128;
        int q3 = pad ? 128 : (int)rintf(v.w * QS) + 128;
        q0 = min(max(q0, 0), 255); q1 = min(max(q1, 0), 255);
        q2 = min(max(q2, 0), 255); q3 = min(max(q3, 0), 255);
        emb8[(size_t)r * 64 + t] = (unsigned)q0 | ((unsigned)q1 << 8) |
                                   ((unsigned)q2 << 16) | ((unsigned)q3 << 24);
        if (t < 8) {
            float pv = emb[(size_t)r * EMBD + 256 + t];
            psqt[r * 8 + t] = pad ? 0.f : pv;
        }
    } else {
        const int e = (blockIdx.x - NR4) * 256 + threadIdx.x;   // 0..65535
        const int bkt = e >> 13, rem = e & 8191;
        const int s = rem >> 10, rem2 = rem & 1023;
        const int nt = rem2 >> 9, rem3 = rem2 & 511;
        const int ln = rem3 >> 3, j = rem3 & 7;
        const int n  = nt * 16 + (ln & 15);
        const int hi = ln >> 4;
        const int k  = s * 32 + hi * 8 + j;
        const float v = w1[(bkt * 32 + n) * 256 + k] + fw1[n * 256 + k];
        w1b[e] = f2bf(v);
        if (e < 256) b1c[e] = b1[e] + fb1[e & 31];
        if (e < 16384) {
            const int jr = e >> 6, i = e & 63;
            float x = 0.f;
            if (i < 31) x = w2[jr * 62 + i];
            else if (i >= 32 && i < 63) x = w2[jr * 62 + i - 1];
            w2p[e] = x;
        }
    }
}

// Sequentially stream emb8 + psqt so every XCD's L2 (and the LLC) is warm
// before the random gathers. slice = (blockIdx>>3)&255 covers the whole table
// per XCD for any round-robin blockIdx->XCD mapping.
__global__ void warm_l2(const unsigned int* __restrict__ emb8,
                        const unsigned int* __restrict__ psqt_u,
                        unsigned int* __restrict__ sink) {
    const unsigned s   = (blockIdx.x >> 3) & 255u;
    const unsigned tid = threadIdx.x;
    unsigned acc = 0;
    // emb8: NROWS*64 = 1,310,784 dwords; slice stride 5124 dwords, 6 iters x 4KB.
#pragma unroll
    for (int i = 0; i < 6; ++i) {
        const unsigned d = s * 5124u + (unsigned)i * 1024u + tid * 4u;
        if (d + 3u < 1310784u) {
            const uint4 v = *((const uint4*)(emb8 + d));
            acc ^= v.x ^ v.y ^ v.z ^ v.w;
        }
    }
    // psqt: NROWS*8 = 163,848 dwords; slice stride 640.
    {
        const unsigned d = s * 640u + tid * 4u;
        if (d + 3u < 163848u) {
            const uint4 v = *((const uint4*)(psqt_u + d));
            acc ^= v.x ^ v.y ^ v.z ^ v.w;
        }
    }
    if (acc == 0x13572468u) sink[0] = acc;   // data-dependent, never-taken sink
}

__global__ __launch_bounds__(256) void nnue_fwd_mfma(
    const unsigned int* __restrict__ emb8,    // (NROWS,64) dwords, biased u8
    const float* __restrict__ psqt,           // (NROWS,8) fp32
    const unsigned short* __restrict__ w1b,   // MFMA B frags, bf16
    const float* __restrict__ b1c,            // folded (256,)
    const float* __restrict__ w2p,            // padded (256,64)
    const float* __restrict__ b2,
    const float* __restrict__ wo,
    const float* __restrict__ bo,
    const float* __restrict__ us,
    const float* __restrict__ them,
    const int*   __restrict__ w_idx,
    const int*   __restrict__ b_idx,
    const int*   __restrict__ pcnt,
    float* __restrict__ out,
    int B)
{
    __shared__ unsigned short A_lds[16 * 280];          // 8960 B
    __shared__ float l1c[8 * 16 * 36];                  // 18432 B
    __shared__ float psq_lds[16];
    __shared__ int   bkt_lds[16];

    const int tid  = threadIdx.x;
    const int lane = tid & 63;
    const int w    = tid >> 6;

    // ---------- phase 1: gather (4 rows per wave), scalar-indexed saddr loads ----------
    for (int rr = 0; rr < 4; ++rr) {
        const int m = w * 4 + rr;
        const int grow = __builtin_amdgcn_readfirstlane(blockIdx.x * 16 + m); // B%16==0

        const float usv = us[grow];
        const float thv = them[grow];
        int bucket = (pcnt[grow] - 1) >> 2;
        bucket = bucket > 7 ? 7 : bucket;
        bucket = __builtin_amdgcn_readfirstlane(bucket);

        const int* wrow = w_idx + grow * 32;   // wave-uniform pointers -> s_load
        const int* brow = b_idx + grow * 32;

        // psqt: per-lane gather (lanes 0..31 w side, 32..63 b side)
        const int kk = lane & 31;
        const int pidx = (lane < 32) ? wrow[kk] : brow[kk];
        float ps = psqt[pidx * 8 + bucket];
        ps += __shfl_xor(ps, 16);
        ps += __shfl_xor(ps, 8);
        ps += __shfl_xor(ps, 4);
        ps += __shfl_xor(ps, 2);
        ps += __shfl_xor(ps, 1);
        const float psq_w = __shfl(ps, 0);
        const float psq_b = __shfl(ps, 32);

        // Gather: every feature row = one wave-wide 256B load, base in SGPRs.
        unsigned aw0 = 0, aw1 = 0, ab0 = 0, ab1 = 0;
        const unsigned M = 0x00FF00FFu;
#pragma unroll
        for (int kb = 0; kb < 32; kb += 16) {
            unsigned vw[16], vb[16];
#pragma unroll
            for (int k2 = 0; k2 < 16; ++k2) {
                const int iw = __builtin_amdgcn_readfirstlane(wrow[kb + k2]);
                vw[k2] = emb8[(size_t)iw * 64 + lane];
            }
#pragma unroll
            for (int k2 = 0; k2 < 16; ++k2) {
                const int ib = __builtin_amdgcn_readfirstlane(brow[kb + k2]);
                vb[k2] = emb8[(size_t)ib * 64 + lane];
            }
#pragma unroll
            for (int k2 = 0; k2 < 16; ++k2) {
                aw0 += vw[k2] & M; aw1 += (vw[k2] >> 8) & M;
                ab0 += vb[k2] & M; ab1 += (vb[k2] >> 8) & M;
            }
        }
        float4 aw, ab;
        aw.x = ((int)(aw0 & 0xffffu) - 4096) * INVQS;
        aw.y = ((int)(aw1 & 0xffffu) - 4096) * INVQS;
        aw.z = ((int)(aw0 >> 16)     - 4096) * INVQS;
        aw.w = ((int)(aw1 >> 16)     - 4096) * INVQS;
        ab.x = ((int)(ab0 & 0xffffu) - 4096) * INVQS;
        ab.y = ((int)(ab1 & 0xffffu) - 4096) * INVQS;
        ab.z = ((int)(ab0 >> 16)     - 4096) * INVQS;
        ab.w = ((int)(ab1 >> 16)     - 4096) * INVQS;

        float4 p, q;
        p.x = clamp01(usv * aw.x + thv * ab.x);
        p.y = clamp01(usv * aw.y + thv * ab.y);
        p.z = clamp01(usv * aw.z + thv * ab.z);
        p.w = clamp01(usv * aw.w + thv * ab.w);
        q.x = clamp01(usv * ab.x + thv * aw.x);
        q.y = clamp01(usv * ab.y + thv * aw.y);
        q.z = clamp01(usv * ab.z + thv * aw.z);
        q.w = clamp01(usv * ab.w + thv * aw.w);

        float4 po, qo;
        po.x = __shfl_xor(p.x, 32); po.y = __shfl_xor(p.y, 32);
        po.z = __shfl_xor(p.z, 32); po.w = __shfl_xor(p.w, 32);
        qo.x = __shfl_xor(q.x, 32); qo.y = __shfl_xor(q.y, 32);
        qo.z = __shfl_xor(q.z, 32); qo.w = __shfl_xor(q.w, 32);
        const float c127 = 127.f / 128.f;
        float4 l0f;
        if (lane < 32) {
            l0f.x = p.x * po.x * c127; l0f.y = p.y * po.y * c127;
            l0f.z = p.z * po.z * c127; l0f.w = p.w * po.w * c127;
        } else {
            l0f.x = q.x * qo.x * c127; l0f.y = q.y * qo.y * c127;
            l0f.z = q.z * qo.z * c127; l0f.w = q.w * qo.w * c127;
        }

        const unsigned lo  = (unsigned)f2bf(l0f.x) | ((unsigned)f2bf(l0f.y) << 16);
        const unsigned hi2 = (unsigned)f2bf(l0f.z) | ((unsigned)f2bf(l0f.w) << 16);
        *((unsigned long long*)&A_lds[m * 280 + lane * 4]) =
            ((unsigned long long)hi2 << 32) | (unsigned long long)lo;
        if (lane == 0) {
            psq_lds[m] = (psq_w - psq_b) * (usv - 0.5f);
            bkt_lds[m] = bucket;
        }
    }
    __syncthreads();

    // ---------- phase 2: l1 via MFMA for all 8 buckets (2 per wave) ----------
    {
        const int col = lane & 15;
        const int hi  = lane >> 4;
        f32x4 acc[2][2];
#pragma unroll
        for (int bb = 0; bb < 2; ++bb)
#pragma unroll
            for (int nt = 0; nt < 2; ++nt)
                acc[bb][nt] = (f32x4){0.f, 0.f, 0.f, 0.f};

#pragma unroll
        for (int s = 0; s < 8; ++s) {
            const short8 a = *((const short8*)&A_lds[col * 280 + s * 32 + hi * 8]);
#pragma unroll
            for (int bb = 0; bb < 2; ++bb) {
                const int bkt = w * 2 + bb;
#pragma unroll
                for (int nt = 0; nt < 2; ++nt) {
                    const short8 bf = *((const short8*)&w1b[(((bkt * 8 + s) * 2 + nt) * 64 + lane) * 8]);
                    acc[bb][nt] = __builtin_amdgcn_mfma_f32_16x16x32_bf16(a, bf, acc[bb][nt], 0, 0, 0);
                }
            }
        }
#pragma unroll
        for (int bb = 0; bb < 2; ++bb) {
            const int bkt = w * 2 + bb;
#pragma unroll
            for (int nt = 0; nt < 2; ++nt) {
                const float bias = b1c[bkt * 32 + nt * 16 + col];
#pragma unroll
                for (int reg = 0; reg < 4; ++reg) {
                    const int mr = hi * 4 + reg;
                    l1c[(bkt * 16 + mr) * 36 + nt * 16 + col] = acc[bb][nt][reg] + bias;
                }
            }
        }
    }
    __syncthreads();

    // ---------- phase 3: l2 + l3, thread = (row, output-pair) ----------
    {
        const int row = tid >> 4;
        const int jj  = tid & 15;
        const int bkt = bkt_lds[row];
        const float4* crow = (const float4*)&l1c[(bkt * 16 + row) * 36];
        float4 c4[8];
#pragma unroll
        for (int b5 = 0; b5 < 8; ++b5) c4[b5] = crow[b5];

        const float4* wr0 = (const float4*)&w2p[(bkt * 32 + jj) * 64];
        const float4* wr1 = (const float4*)&w2p[(bkt * 32 + jj + 16) * 64];
        float acc0 = 0.f, acc1 = 0.f;
        const float kq = 255.f / 256.f;
#pragma unroll
        for (int b5 = 0; b5 < 8; ++b5) {
            const float4 cv = c4[b5];
            float4 sq, ln;
            sq.x = clamp01(cv.x * cv.x * kq); ln.x = clamp01(cv.x);
            sq.y = clamp01(cv.y * cv.y * kq); ln.y = clamp01(cv.y);
            sq.z = clamp01(cv.z * cv.z * kq); ln.z = clamp01(cv.z);
            sq.w = clamp01(cv.w * cv.w * kq); ln.w = clamp01(cv.w);
            const float4 ws0 = wr0[b5], wl0 = wr0[8 + b5];
            const float4 ws1 = wr1[b5], wl1 = wr1[8 + b5];
            acc0 += sq.x * ws0.x + sq.y * ws0.y + sq.z * ws0.z + sq.w * ws0.w;
            acc0 += ln.x * wl0.x + ln.y * wl0.y + ln.z * wl0.z + ln.w * wl0.w;
            acc1 += sq.x * ws1.x + sq.y * ws1.y + sq.z * ws1.z + sq.w * ws1.w;
            acc1 += ln.x * wl1.x + ln.y * wl1.y + ln.z * wl1.z + ln.w * wl1.w;
        }
        const float t0 = clamp01(acc0 + b2[bkt * 32 + jj])      * wo[bkt * 32 + jj];
        const float t1 = clamp01(acc1 + b2[bkt * 32 + jj + 16]) * wo[bkt * 32 + jj + 16];
        float t = t0 + t1;
        t += __shfl_xor(t, 8);
        t += __shfl_xor(t, 4);
        t += __shfl_xor(t, 2);
        t += __shfl_xor(t, 1);
        if (jj == 0) {
            out[blockIdx.x * 16 + row] = t + bo[bkt] + c4[7].w + psq_lds[row];
        }
    }
}

// ---------- fp32 fallback (self-contained, no workspace) ----------
__global__ __launch_bounds__(256) void nnue_fwd_f32(
    const float* __restrict__ emb,
    const float* __restrict__ w1e, const float* __restrict__ fw1,
    const float* __restrict__ b1e, const float* __restrict__ fb1,
    const float* __restrict__ w2,  const float* __restrict__ b2,
    const float* __restrict__ wo,  const float* __restrict__ bo,
    const float* __restrict__ us,  const float* __restrict__ them,
    const int* __restrict__ w_idx, const int* __restrict__ b_idx,
    const int* __restrict__ pcnt,  float* __restrict__ out, int B)
{
    const int lane = threadIdx.x & 63;
    const int row  = blockIdx.x * 4 + (threadIdx.x >> 6);
    if (row >= B) return;
    const float usv = us[row];
    const float thv = them[row];
    int bucket = (pcnt[row] - 1) >> 2;
    bucket = bucket > 7 ? 7 : bucket;
    bucket = __builtin_amdgcn_readfirstlane(bucket);
    const int kk = lane & 31;
    const int myidx = (lane < 32) ? w_idx[row * 32 + kk] : b_idx[row * 32 + kk];
    float ps = emb[(size_t)myidx * EMBD + 256 + bucket];
    ps += __shfl_xor(ps, 16); ps += __shfl_xor(ps, 8);
    ps += __shfl_xor(ps, 4);  ps += __shfl_xor(ps, 2); ps += __shfl_xor(ps, 1);
    const float psq_w = __shfl(ps, 0);
    const float psq_b = __shfl(ps, 32);
    float4 aw = make_float4(0,0,0,0), ab = make_float4(0,0,0,0);
#pragma unroll
    for (int k = 0; k < 32; ++k) {
        const int iw = __shfl(myidx, k);
        const int ib = __shfl(myidx, 32 + k);
        const float4 vw = *((const float4*)(emb + (size_t)iw * EMBD) + lane);
        const float4 vb = *((const float4*)(emb + (size_t)ib * EMBD) + lane);
        aw.x += vw.x; aw.y += vw.y; aw.z += vw.z; aw.w += vw.w;
        ab.x += vb.x; ab.y += vb.y; ab.z += vb.z; ab.w += vb.w;
    }
    float4 p, q;
    p.x = clamp01(usv*aw.x + thv*ab.x); p.y = clamp01(usv*aw.y + thv*ab.y);
    p.z = clamp01(usv*aw.z + thv*ab.z); p.w = clamp01(usv*aw.w + thv*ab.w);
    q.x = clamp01(usv*ab.x + thv*aw.x); q.y = clamp01(usv*ab.y + thv*aw.y);
    q.z = clamp01(usv*ab.z + thv*aw.z); q.w = clamp01(usv*ab.w + thv*aw.w);
    float4 po, qo;
    po.x = __shfl_xor(p.x,32); po.y = __shfl_xor(p.y,32);
    po.z = __shfl_xor(p.z,32); po.w = __shfl_xor(p.w,32);
    qo.x = __shfl_xor(q.x,32); qo.y = __shfl_xor(q.y,32);
    qo.z = __shfl_xor(q.z,32); qo.w = __shfl_xor(q.w,32);
    const float c127 = 127.f/128.f;
    float4 l0f;
    if (lane < 32) { l0f.x=p.x*po.x*c127; l0f.y=p.y*po.y*c127; l0f.z=p.z*po.z*c127; l0f.w=p.w*po.w*c127; }
    else           { l0f.x=q.x*qo.x*c127; l0f.y=q.y*qo.y*c127; l0f.z=q.z*qo.z*c127; l0f.w=q.w*qo.w*c127; }
    float part[32];
    const float4* w1p = (const float4*)(w1e + (size_t)bucket * 8192);
    const float4* f1p = (const float4*)fw1;
#pragma unroll
    for (int j = 0; j < 32; ++j) {
        float4 wv = w1p[j*64 + lane];
        float4 fv = f1p[j*64 + lane];
        wv.x+=fv.x; wv.y+=fv.y; wv.z+=fv.z; wv.w+=fv.w;
        part[j] = l0f.x*wv.x + l0f.y*wv.y + l0f.z*wv.z + l0f.w*wv.w;
    }
#pragma unroll
    for (int j = 0; j < 32; ++j) {
        float v = part[j];
        v += __shfl_xor(v,32); v += __shfl_xor(v,16); v += __shfl_xor(v,8);
        v += __shfl_xor(v,4);  v += __shfl_xor(v,2);  v += __shfl_xor(v,1);
        part[j] = v + b1e[bucket*32 + j] + fb1[j];
    }
    const float l1x_out = part[31];
    float acc2 = 0.f;
    if (lane < 32) {
        const float* w2r = w2 + (size_t)(bucket*32 + lane) * 62;
#pragma unroll
        for (int i = 0; i < 31; ++i) {
            const float a = part[i];
            acc2 += clamp01(a*a*(255.f/256.f)) * w2r[i];
            acc2 += clamp01(a) * w2r[31+i];
        }
        acc2 += b2[bucket*32 + lane];
        acc2 = clamp01(acc2) * wo[bucket*32 + lane];
    }
    acc2 += __shfl_xor(acc2,16); acc2 += __shfl_xor(acc2,8);
    acc2 += __shfl_xor(acc2,4);  acc2 += __shfl_xor(acc2,2); acc2 += __shfl_xor(acc2,1);
    if (lane == 0)
        out[row] = acc2 + bo[bucket] + l1x_out + (psq_w - psq_b) * (usv - 0.5f);
}

extern "C" void kernel_launch(void* const* d_in, const int* in_sizes, int n_in,
                              void* d_out, int out_size, void* d_ws, size_t ws_size,
                              hipStream_t stream) {
    const float* emb  = (const float*)d_in[0];
    const float* w1   = (const float*)d_in[1];
    const float* b1   = (const float*)d_in[2];
    const float* fw1  = (const float*)d_in[3];
    const float* fb1  = (const float*)d_in[4];
    const float* w2   = (const float*)d_in[5];
    const float* b2   = (const float*)d_in[6];
    const float* wo   = (const float*)d_in[7];
    const float* bo   = (const float*)d_in[8];
    const float* us   = (const float*)d_in[9];
    const float* them = (const float*)d_in[10];
    const int*   wi   = (const int*)d_in[11];
    const int*   bi   = (const int*)d_in[12];
    const int*   pc   = (const int*)d_in[13];
    float* out = (float*)d_out;

    const int B = in_sizes[9];               // 16384

    const size_t emb8_bytes = (size_t)NROWS * 256;   // 5,243,136
    const size_t psqt_bytes = (size_t)NROWS * 8 * 4; //   655,392
    const size_t w1b_bytes  = 65536 * 2;
    const size_t b1c_bytes  = 256 * 4;
    const size_t w2p_bytes  = 16384 * 4;
    const size_t sink_bytes = 16;
    const size_t need = emb8_bytes + psqt_bytes + w1b_bytes + b1c_bytes +
                        w2p_bytes + sink_bytes;

    if (ws_size >= need && (B % 16) == 0) {
        char* p = (char*)d_ws;
        unsigned int*   emb8 = (unsigned int*)p;     p += emb8_bytes;
        float*          psqt = (float*)p;            p += psqt_bytes;
        unsigned short* w1b  = (unsigned short*)p;   p += w1b_bytes;
        float*          b1c  = (float*)p;            p += b1c_bytes;
        float*          w2p  = (float*)p;            p += w2p_bytes;
        unsigned int*   sink = (unsigned int*)p;

        prep_all<<<NR4 + 256, 256, 0, stream>>>(emb, emb8, psqt,
                                                w1, fw1, b1, fb1, w2, w1b, b1c, w2p);
        warm_l2<<<2048, 256, 0, stream>>>(emb8, (const unsigned int*)psqt, sink);
        nnue_fwd_mfma<<<B / 16, 256, 0, stream>>>(emb8, psqt, w1b, b1c, w2p,
                                                  b2, wo, bo, us, them, wi, bi, pc, out, B);
    } else {
        nnue_fwd_f32<<<(B + 3) / 4, 256, 0, stream>>>(emb, w1, fw1, b1, fb1,
                                                      w2, b2, wo, bo, us, them, wi, bi, pc, out, B);
    }
}

// Round 9
// 137.189 us; speedup vs baseline: 1.0835x; 1.0434x over previous
//
#include <hip/hip_runtime.h>

#define EMBD 264        // L1(256) + 8 psqt
#define NROWS 20481     // HALFKP+1
#define NR4   5121      // ceil(NROWS/4)
#define QS 5080.0f      // int8 scale: 127/0.025
#define INVQS (1.0f/5080.0f)

typedef short short8 __attribute__((ext_vector_type(8)));
typedef float f32x4  __attribute__((ext_vector_type(4)));

__device__ __forceinline__ float clamp01(float x) { return fminf(fmaxf(x, 0.f), 1.f); }
__device__ __forceinline__ unsigned short f2bf(float f) {
    unsigned u = __float_as_uint(f);
    u += 0x7fffu + ((u >> 16) & 1u);   // RNE
    return (unsigned short)(u >> 16);
}

// Merged prep: blocks [0, NR4) quantize emb -> embA (cols 0..127) / embB (cols
// 128..255), biased-u8, 128 B (one cache line) per row; psqt (NROWS,8) fp32.
// Blocks [NR4, NR4+256) build w1b (folded bf16 MFMA B-frags), b1c, w2p.
__global__ void prep_all(const float* __restrict__ emb,
                         unsigned int* __restrict__ embA, unsigned int* __restrict__ embB,
                         float* __restrict__ psqt,
                         const float* __restrict__ w1, const float* __restrict__ fw1,
                         const float* __restrict__ b1, const float* __restrict__ fb1,
                         const float* __restrict__ w2,
                         unsigned short* __restrict__ w1b, float* __restrict__ b1c,
                         float* __restrict__ w2p) {
    if (blockIdx.x < NR4) {
        const int r = blockIdx.x * 4 + (threadIdx.x >> 6);
        const int t = threadIdx.x & 63;
        if (r >= NROWS) return;
        const bool pad = (r == NROWS - 1);
        const float4 v = *((const float4*)(emb + (size_t)r * EMBD) + t);
        int q0 = pad ? 128 : (int)rintf(v.x * QS) + 128;
        int q1 = pad ? 128 : (int)rintf(v.y * QS) + 128;
        int q2 = pad ? 128 : (int)rintf(v.z * QS) + 128;
        int q3 = pad ? 128 : (int)rintf(v.w * QS) + 128;
        q0 = min(max(q0, 0), 255); q1 = min(max(q1, 0), 255);
        q2 = min(max(q2, 0), 255); q3 = min(max(q3, 0), 255);
        const unsigned packed = (unsigned)q0 | ((unsigned)q1 << 8) |
                                ((unsigned)q2 << 16) | ((unsigned)q3 << 24);
        if (t < 32) embA[(size_t)r * 32 + t] = packed;
        else        embB[(size_t)r * 32 + (t - 32)] = packed;
        if (t < 8) {
            float pv = emb[(size_t)r * EMBD + 256 + t];
            psqt[r * 8 + t] = pad ? 0.f : pv;
        }
    } else {
        const int e = (blockIdx.x - NR4) * 256 + threadIdx.x;   // 0..65535
        const int bkt = e >> 13, rem = e & 8191;
        const int s = rem >> 10, rem2 = rem & 1023;
        const int nt = rem2 >> 9, rem3 = rem2 & 511;
        const int ln = rem3 >> 3, j = rem3 & 7;
        const int n  = nt * 16 + (ln & 15);
        const int hi = ln >> 4;
        const int k  = s * 32 + hi * 8 + j;
        const float v = w1[(bkt * 32 + n) * 256 + k] + fw1[n * 256 + k];
        w1b[e] = f2bf(v);
        if (e < 256) b1c[e] = b1[e] + fb1[e & 31];
        if (e < 16384) {
            const int jr = e >> 6, i = e & 63;
            float x = 0.f;
            if (i < 31) x = w2[jr * 62 + i];
            else if (i >= 32 && i < 63) x = w2[jr * 62 + i - 1];
            w2p[e] = x;
        }
    }
}

__global__ __launch_bounds__(256) void nnue_fwd_mfma(
    const unsigned int* __restrict__ embA,    // (NROWS,32) dwords, cols 0..127
    const unsigned int* __restrict__ embB,    // (NROWS,32) dwords, cols 128..255
    const float* __restrict__ psqt,           // (NROWS,8) fp32
    const unsigned short* __restrict__ w1b,   // MFMA B frags, bf16
    const float* __restrict__ b1c,            // folded (256,)
    const float* __restrict__ w2p,            // padded (256,64)
    const float* __restrict__ b2,
    const float* __restrict__ wo,
    const float* __restrict__ bo,
    const float* __restrict__ us,
    const float* __restrict__ them,
    const int*   __restrict__ w_idx,
    const int*   __restrict__ b_idx,
    const int*   __restrict__ pcnt,
    float* __restrict__ out,
    int B)
{
    __shared__ unsigned short A_lds[16 * 280];          // 8960 B
    __shared__ float l1c[8 * 16 * 36];                  // 18432 B
    __shared__ float psq_lds[16];
    __shared__ int   bkt_lds[16];

    const int tid  = threadIdx.x;
    const int lane = tid & 63;
    const int w    = tid >> 6;
    const int g    = lane & 31;       // column group within a half

    // ---------- phase 1: gather (4 rows per wave), two L2-resident passes ----------
    for (int rr = 0; rr < 4; ++rr) {
        const int m = w * 4 + rr;
        const int grow = __builtin_amdgcn_readfirstlane(blockIdx.x * 16 + m); // B%16==0

        const float usv = us[grow];
        const float thv = them[grow];
        int bucket = (pcnt[grow] - 1) >> 2;
        bucket = bucket > 7 ? 7 : bucket;
        bucket = __builtin_amdgcn_readfirstlane(bucket);

        const int* wrow = w_idx + grow * 32;   // wave-uniform pointers -> s_load
        const int* brow = b_idx + grow * 32;

        // psqt: per-lane gather (lanes 0..31 w side, 32..63 b side)
        const int pidx = (lane < 32) ? wrow[g] : brow[g];
        float ps = psqt[pidx * 8 + bucket];
        ps += __shfl_xor(ps, 16);
        ps += __shfl_xor(ps, 8);
        ps += __shfl_xor(ps, 4);
        ps += __shfl_xor(ps, 2);
        ps += __shfl_xor(ps, 1);
        const float psq_w = __shfl(ps, 0);
        const float psq_b = __shfl(ps, 32);

        // Two passes over the half-tables. One wave-load covers TWO feature
        // rows (lanes 0..31: feature 2k, lanes 32..63: feature 2k+1); each
        // half-row is exactly one 128-B line of a 2.6-MB (L2-resident) array.
        float4 wsum[2], bsum[2];
#pragma unroll
        for (int h = 0; h < 2; ++h) {
            const unsigned int* T = h ? embB : embA;
            unsigned vw[16], vb[16];
#pragma unroll
            for (int k2 = 0; k2 < 16; ++k2) {
                const int i0 = __builtin_amdgcn_readfirstlane(wrow[2 * k2]);
                const int i1 = __builtin_amdgcn_readfirstlane(wrow[2 * k2 + 1]);
                const int base = (lane < 32) ? i0 : i1;
                vw[k2] = T[(size_t)base * 32 + g];
            }
#pragma unroll
            for (int k2 = 0; k2 < 16; ++k2) {
                const int i0 = __builtin_amdgcn_readfirstlane(brow[2 * k2]);
                const int i1 = __builtin_amdgcn_readfirstlane(brow[2 * k2 + 1]);
                const int base = (lane < 32) ? i0 : i1;
                vb[k2] = T[(size_t)base * 32 + g];
            }
            unsigned s0 = 0, s1 = 0, t0 = 0, t1 = 0;
            const unsigned M = 0x00FF00FFu;
#pragma unroll
            for (int k2 = 0; k2 < 16; ++k2) {
                s0 += vw[k2] & M; s1 += (vw[k2] >> 8) & M;
                t0 += vb[k2] & M; t1 += (vb[k2] >> 8) & M;
            }
            // combine even/odd-feature halves (<=16*255 each, sum <= 8160: exact)
            s0 += __shfl_xor(s0, 32); s1 += __shfl_xor(s1, 32);
            t0 += __shfl_xor(t0, 32); t1 += __shfl_xor(t1, 32);
            wsum[h].x = ((int)(s0 & 0xffffu) - 4096) * INVQS;
            wsum[h].y = ((int)(s1 & 0xffffu) - 4096) * INVQS;
            wsum[h].z = ((int)(s0 >> 16)     - 4096) * INVQS;
            wsum[h].w = ((int)(s1 >> 16)     - 4096) * INVQS;
            bsum[h].x = ((int)(t0 & 0xffffu) - 4096) * INVQS;
            bsum[h].y = ((int)(t1 & 0xffffu) - 4096) * INVQS;
            bsum[h].z = ((int)(t0 >> 16)     - 4096) * INVQS;
            bsum[h].w = ((int)(t1 >> 16)     - 4096) * INVQS;
        }

        // l0 + crosslink, fully lane-local: cols 4g..4g+3 (half0) pair with
        // cols 128+4g..+3 (half1).
        float4 plo, phi, qlo, qhi;
        plo.x = clamp01(usv * wsum[0].x + thv * bsum[0].x);
        plo.y = clamp01(usv * wsum[0].y + thv * bsum[0].y);
        plo.z = clamp01(usv * wsum[0].z + thv * bsum[0].z);
        plo.w = clamp01(usv * wsum[0].w + thv * bsum[0].w);
        phi.x = clamp01(usv * wsum[1].x + thv * bsum[1].x);
        phi.y = clamp01(usv * wsum[1].y + thv * bsum[1].y);
        phi.z = clamp01(usv * wsum[1].z + thv * bsum[1].z);
        phi.w = clamp01(usv * wsum[1].w + thv * bsum[1].w);
        qlo.x = clamp01(usv * bsum[0].x + thv * wsum[0].x);
        qlo.y = clamp01(usv * bsum[0].y + thv * wsum[0].y);
        qlo.z = clamp01(usv * bsum[0].z + thv * wsum[0].z);
        qlo.w = clamp01(usv * bsum[0].w + thv * wsum[0].w);
        qhi.x = clamp01(usv * bsum[1].x + thv * wsum[1].x);
        qhi.y = clamp01(usv * bsum[1].y + thv * wsum[1].y);
        qhi.z = clamp01(usv * bsum[1].z + thv * wsum[1].z);
        qhi.w = clamp01(usv * bsum[1].w + thv * wsum[1].w);
        const float c127 = 127.f / 128.f;

        if (lane < 32) {
            const unsigned aLo = (unsigned)f2bf(plo.x * phi.x * c127) |
                                 ((unsigned)f2bf(plo.y * phi.y * c127) << 16);
            const unsigned aHi = (unsigned)f2bf(plo.z * phi.z * c127) |
                                 ((unsigned)f2bf(plo.w * phi.w * c127) << 16);
            *((unsigned long long*)&A_lds[m * 280 + g * 4]) =
                ((unsigned long long)aHi << 32) | (unsigned long long)aLo;
            const unsigned bLo = (unsigned)f2bf(qlo.x * qhi.x * c127) |
                                 ((unsigned)f2bf(qlo.y * qhi.y * c127) << 16);
            const unsigned bHi = (unsigned)f2bf(qlo.z * qhi.z * c127) |
                                 ((unsigned)f2bf(qlo.w * qhi.w * c127) << 16);
            *((unsigned long long*)&A_lds[m * 280 + 128 + g * 4]) =
                ((unsigned long long)bHi << 32) | (unsigned long long)bLo;
        }
        if (lane == 0) {
            psq_lds[m] = (psq_w - psq_b) * (usv - 0.5f);
            bkt_lds[m] = bucket;
        }
    }
    __syncthreads();

    // ---------- phase 2: l1 via MFMA for all 8 buckets (2 per wave) ----------
    {
        const int col = lane & 15;
        const int hi  = lane >> 4;
        f32x4 acc[2][2];
#pragma unroll
        for (int bb = 0; bb < 2; ++bb)
#pragma unroll
            for (int nt = 0; nt < 2; ++nt)
                acc[bb][nt] = (f32x4){0.f, 0.f, 0.f, 0.f};

#pragma unroll
        for (int s = 0; s < 8; ++s) {
            const short8 a = *((const short8*)&A_lds[col * 280 + s * 32 + hi * 8]);
#pragma unroll
            for (int bb = 0; bb < 2; ++bb) {
                const int bkt = w * 2 + bb;
#pragma unroll
                for (int nt = 0; nt < 2; ++nt) {
                    const short8 bf = *((const short8*)&w1b[(((bkt * 8 + s) * 2 + nt) * 64 + lane) * 8]);
                    acc[bb][nt] = __builtin_amdgcn_mfma_f32_16x16x32_bf16(a, bf, acc[bb][nt], 0, 0, 0);
                }
            }
        }
#pragma unroll
        for (int bb = 0; bb < 2; ++bb) {
            const int bkt = w * 2 + bb;
#pragma unroll
            for (int nt = 0; nt < 2; ++nt) {
                const float bias = b1c[bkt * 32 + nt * 16 + col];
#pragma unroll
                for (int reg = 0; reg < 4; ++reg) {
                    const int mr = hi * 4 + reg;
                    l1c[(bkt * 16 + mr) * 36 + nt * 16 + col] = acc[bb][nt][reg] + bias;
                }
            }
        }
    }
    __syncthreads();

    // ---------- phase 3: l2 + l3, thread = (row, output-pair) ----------
    {
        const int row = tid >> 4;
        const int jj  = tid & 15;
        const int bkt = bkt_lds[row];
        const float4* crow = (const float4*)&l1c[(bkt * 16 + row) * 36];
        float4 c4[8];
#pragma unroll
        for (int b5 = 0; b5 < 8; ++b5) c4[b5] = crow[b5];

        const float4* wr0 = (const float4*)&w2p[(bkt * 32 + jj) * 64];
        const float4* wr1 = (const float4*)&w2p[(bkt * 32 + jj + 16) * 64];
        float acc0 = 0.f, acc1 = 0.f;
        const float kq = 255.f / 256.f;
#pragma unroll
        for (int b5 = 0; b5 < 8; ++b5) {
            const float4 cv = c4[b5];
            float4 sq, ln;
            sq.x = clamp01(cv.x * cv.x * kq); ln.x = clamp01(cv.x);
            sq.y = clamp01(cv.y * cv.y * kq); ln.y = clamp01(cv.y);
            sq.z = clamp01(cv.z * cv.z * kq); ln.z = clamp01(cv.z);
            sq.w = clamp01(cv.w * cv.w * kq); ln.w = clamp01(cv.w);
            const float4 ws0 = wr0[b5], wl0 = wr0[8 + b5];
            const float4 ws1 = wr1[b5], wl1 = wr1[8 + b5];
            acc0 += sq.x * ws0.x + sq.y * ws0.y + sq.z * ws0.z + sq.w * ws0.w;
            acc0 += ln.x * wl0.x + ln.y * wl0.y + ln.z * wl0.z + ln.w * wl0.w;
            acc1 += sq.x * ws1.x + sq.y * ws1.y + sq.z * ws1.z + sq.w * ws1.w;
            acc1 += ln.x * wl1.x + ln.y * wl1.y + ln.z * wl1.z + ln.w * wl1.w;
        }
        const float t0 = clamp01(acc0 + b2[bkt * 32 + jj])      * wo[bkt * 32 + jj];
        const float t1 = clamp01(acc1 + b2[bkt * 32 + jj + 16]) * wo[bkt * 32 + jj + 16];
        float t = t0 + t1;
        t += __shfl_xor(t, 8);
        t += __shfl_xor(t, 4);
        t += __shfl_xor(t, 2);
        t += __shfl_xor(t, 1);
        if (jj == 0) {
            out[blockIdx.x * 16 + row] = t + bo[bkt] + c4[7].w + psq_lds[row];
        }
    }
}

// ---------- fp32 fallback (self-contained, no workspace) ----------
__global__ __launch_bounds__(256) void nnue_fwd_f32(
    const float* __restrict__ emb,
    const float* __restrict__ w1e, const float* __restrict__ fw1,
    const float* __restrict__ b1e, const float* __restrict__ fb1,
    const float* __restrict__ w2,  const float* __restrict__ b2,
    const float* __restrict__ wo,  const float* __restrict__ bo,
    const float* __restrict__ us,  const float* __restrict__ them,
    const int* __restrict__ w_idx, const int* __restrict__ b_idx,
    const int* __restrict__ pcnt,  float* __restrict__ out, int B)
{
    const int lane = threadIdx.x & 63;
    const int row  = blockIdx.x * 4 + (threadIdx.x >> 6);
    if (row >= B) return;
    const float usv = us[row];
    const float thv = them[row];
    int bucket = (pcnt[row] - 1) >> 2;
    bucket = bucket > 7 ? 7 : bucket;
    bucket = __builtin_amdgcn_readfirstlane(bucket);
    const int kk = lane & 31;
    const int myidx = (lane < 32) ? w_idx[row * 32 + kk] : b_idx[row * 32 + kk];
    float ps = emb[(size_t)myidx * EMBD + 256 + bucket];
    ps += __shfl_xor(ps, 16); ps += __shfl_xor(ps, 8);
    ps += __shfl_xor(ps, 4);  ps += __shfl_xor(ps, 2); ps += __shfl_xor(ps, 1);
    const float psq_w = __shfl(ps, 0);
    const float psq_b = __shfl(ps, 32);
    float4 aw = make_float4(0,0,0,0), ab = make_float4(0,0,0,0);
#pragma unroll
    for (int k = 0; k < 32; ++k) {
        const int iw = __shfl(myidx, k);
        const int ib = __shfl(myidx, 32 + k);
        const float4 vw = *((const float4*)(emb + (size_t)iw * EMBD) + lane);
        const float4 vb = *((const float4*)(emb + (size_t)ib * EMBD) + lane);
        aw.x += vw.x; aw.y += vw.y; aw.z += vw.z; aw.w += vw.w;
        ab.x += vb.x; ab.y += vb.y; ab.z += vb.z; ab.w += vb.w;
    }
    float4 p, q;
    p.x = clamp01(usv*aw.x + thv*ab.x); p.y = clamp01(usv*aw.y + thv*ab.y);
    p.z = clamp01(usv*aw.z + thv*ab.z); p.w = clamp01(usv*aw.w + thv*ab.w);
    q.x = clamp01(usv*ab.x + thv*aw.x); q.y = clamp01(usv*ab.y + thv*aw.y);
    q.z = clamp01(usv*ab.z + thv*aw.z); q.w = clamp01(usv*ab.w + thv*aw.w);
    float4 po, qo;
    po.x = __shfl_xor(p.x,32); po.y = __shfl_xor(p.y,32);
    po.z = __shfl_xor(p.z,32); po.w = __shfl_xor(p.w,32);
    qo.x = __shfl_xor(q.x,32); qo.y = __shfl_xor(q.y,32);
    qo.z = __shfl_xor(q.z,32); qo.w = __shfl_xor(q.w,32);
    const float c127 = 127.f/128.f;
    float4 l0f;
    if (lane < 32) { l0f.x=p.x*po.x*c127; l0f.y=p.y*po.y*c127; l0f.z=p.z*po.z*c127; l0f.w=p.w*po.w*c127; }
    else           { l0f.x=q.x*qo.x*c127; l0f.y=q.y*qo.y*c127; l0f.z=q.z*qo.z*c127; l0f.w=q.w*qo.w*c127; }
    float part[32];
    const float4* w1p = (const float4*)(w1e + (size_t)bucket * 8192);
    const float4* f1p = (const float4*)fw1;
#pragma unroll
    for (int j = 0; j < 32; ++j) {
        float4 wv = w1p[j*64 + lane];
        float4 fv = f1p[j*64 + lane];
        wv.x+=fv.x; wv.y+=fv.y; wv.z+=fv.z; wv.w+=fv.w;
        part[j] = l0f.x*wv.x + l0f.y*wv.y + l0f.z*wv.z + l0f.w*wv.w;
    }
#pragma unroll
    for (int j = 0; j < 32; ++j) {
        float v = part[j];
        v += __shfl_xor(v,32); v += __shfl_xor(v,16); v += __shfl_xor(v,8);
        v += __shfl_xor(v,4);  v += __shfl_xor(v,2);  v += __shfl_xor(v,1);
        part[j] = v + b1e[bucket*32 + j] + fb1[j];
    }
    const float l1x_out = part[31];
    float acc2 = 0.f;
    if (lane < 32) {
        const float* w2r = w2 + (size_t)(bucket*32 + lane) * 62;
#pragma unroll
        for (int i = 0; i < 31; ++i) {
            const float a = part[i];
            acc2 += clamp01(a*a*(255.f/256.f)) * w2r[i];
            acc2 += clamp01(a) * w2r[31+i];
        }
        acc2 += b2[bucket*32 + lane];
        acc2 = clamp01(acc2) * wo[bucket*32 + lane];
    }
    acc2 += __shfl_xor(acc2,16); acc2 += __shfl_xor(acc2,8);
    acc2 += __shfl_xor(acc2,4);  acc2 += __shfl_xor(acc2,2); acc2 += __shfl_xor(acc2,1);
    if (lane == 0)
        out[row] = acc2 + bo[bucket] + l1x_out + (psq_w - psq_b) * (usv - 0.5f);
}

extern "C" void kernel_launch(void* const* d_in, const int* in_sizes, int n_in,
                              void* d_out, int out_size, void* d_ws, size_t ws_size,
                              hipStream_t stream) {
    const float* emb  = (const float*)d_in[0];
    const float* w1   = (const float*)d_in[1];
    const float* b1   = (const float*)d_in[2];
    const float* fw1  = (const float*)d_in[3];
    const float* fb1  = (const float*)d_in[4];
    const float* w2   = (const float*)d_in[5];
    const float* b2   = (const float*)d_in[6];
    const float* wo   = (const float*)d_in[7];
    const float* bo   = (const float*)d_in[8];
    const float* us   = (const float*)d_in[9];
    const float* them = (const float*)d_in[10];
    const int*   wi   = (const int*)d_in[11];
    const int*   bi   = (const int*)d_in[12];
    const int*   pc   = (const int*)d_in[13];
    float* out = (float*)d_out;

    const int B = in_sizes[9];               // 16384

    const size_t half_bytes = (size_t)NROWS * 128;   // 2,621,568 each
    const size_t psqt_bytes = (size_t)NROWS * 8 * 4; //   655,392
    const size_t w1b_bytes  = 65536 * 2;
    const size_t b1c_bytes  = 256 * 4;
    const size_t w2p_bytes  = 16384 * 4;
    const size_t need = 2 * half_bytes + psqt_bytes + w1b_bytes + b1c_bytes + w2p_bytes;

    if (ws_size >= need && (B % 16) == 0) {
        char* p = (char*)d_ws;
        unsigned int*   embA = (unsigned int*)p;     p += half_bytes;
        unsigned int*   embB = (unsigned int*)p;     p += half_bytes;
        float*          psqt = (float*)p;            p += psqt_bytes;
        unsigned short* w1b  = (unsigned short*)p;   p += w1b_bytes;
        float*          b1c  = (float*)p;            p += b1c_bytes;
        float*          w2p  = (float*)p;

        prep_all<<<NR4 + 256, 256, 0, stream>>>(emb, embA, embB, psqt,
                                                w1, fw1, b1, fb1, w2, w1b, b1c, w2p);
        nnue_fwd_mfma<<<B / 16, 256, 0, stream>>>(embA, embB, psqt, w1b, b1c, w2p,
                                                  b2, wo, bo, us, them, wi, bi, pc, out, B);
    } else {
        nnue_fwd_f32<<<(B + 3) / 4, 256, 0, stream>>>(emb, w1, fw1, b1, fb1,
                                                      w2, b2, wo, bo, us, them, wi, bi, pc, out, B);
    }
}

// Round 10
// 136.907 us; speedup vs baseline: 1.0858x; 1.0021x over previous
//
#include <hip/hip_runtime.h>

#define EMBD 264        // L1(256) + 8 psqt
#define NROWS 20481     // HALFKP+1
#define NR4   5121      // ceil(NROWS/4)
#define QS 5080.0f      // int8 scale: 127/0.025
#define INVQS (1.0f/5080.0f)

typedef short short8 __attribute__((ext_vector_type(8)));
typedef float f32x4  __attribute__((ext_vector_type(4)));

__device__ __forceinline__ float clamp01(float x) { return fminf(fmaxf(x, 0.f), 1.f); }
__device__ __forceinline__ unsigned short f2bf(float f) {
    unsigned u = __float_as_uint(f);
    u += 0x7fffu + ((u >> 16) & 1u);   // RNE
    return (unsigned short)(u >> 16);
}

// Merged prep: blocks [0, NR4) quantize emb -> emb8/psqt; blocks [NR4, NR4+256)
// build w1b (folded bf16 MFMA B-frags), b1c, w2p.
__global__ void prep_all(const float* __restrict__ emb, unsigned int* __restrict__ emb8,
                         float* __restrict__ psqt,
                         const float* __restrict__ w1, const float* __restrict__ fw1,
                         const float* __restrict__ b1, const float* __restrict__ fb1,
                         const float* __restrict__ w2,
                         unsigned short* __restrict__ w1b, float* __restrict__ b1c,
                         float* __restrict__ w2p) {
    if (blockIdx.x < NR4) {
        const int r = blockIdx.x * 4 + (threadIdx.x >> 6);
        const int t = threadIdx.x & 63;
        if (r >= NROWS) return;
        const bool pad = (r == NROWS - 1);
        const float4 v = *((const float4*)(emb + (size_t)r * EMBD) + t);
        int q0 = pad ? 128 : (int)rintf(v.x * QS) + 128;
        int q1 = pad ? 128 : (int)rintf(v.y * QS) + 128;
        int q2 = pad ? 128 : (int)rintf(v.z * QS) + 128;
        int q3 = pad ? 128 : (int)rintf(v.w * QS) + 128;
        q0 = min(max(q0, 0), 255); q1 = min(max(q1, 0), 255);
        q2 = min(max(q2, 0), 255); q3 = min(max(q3, 0), 255);
        emb8[(size_t)r * 64 + t] = (unsigned)q0 | ((unsigned)q1 << 8) |
                                   ((unsigned)q2 << 16) | ((unsigned)q3 << 24);
        if (t < 8) {
            float pv = emb[(size_t)r * EMBD + 256 + t];
            psqt[r * 8 + t] = pad ? 0.f : pv;
        }
    } else {
        const int e = (blockIdx.x - NR4) * 256 + threadIdx.x;   // 0..65535
        const int bkt = e >> 13, rem = e & 8191;
        const int s = rem >> 10, rem2 = rem & 1023;
        const int nt = rem2 >> 9, rem3 = rem2 & 511;
        const int ln = rem3 >> 3, j = rem3 & 7;
        const int n  = nt * 16 + (ln & 15);
        const int hi = ln >> 4;
        const int k  = s * 32 + hi * 8 + j;
        const float v = w1[(bkt * 32 + n) * 256 + k] + fw1[n * 256 + k];
        w1b[e] = f2bf(v);
        if (e < 256) b1c[e] = b1[e] + fb1[e & 31];
        if (e < 16384) {
            const int jr = e >> 6, i = e & 63;
            float x = 0.f;
            if (i < 31) x = w2[jr * 62 + i];
            else if (i >= 32 && i < 63) x = w2[jr * 62 + i - 1];
            w2p[e] = x;
        }
    }
}

__global__ __launch_bounds__(512) void nnue_fwd_mfma(
    const unsigned int* __restrict__ emb8,    // (NROWS,64) dwords, biased u8
    const float* __restrict__ psqt,           // (NROWS,8) fp32
    const unsigned short* __restrict__ w1b,   // MFMA B frags, bf16
    const float* __restrict__ b1c,            // folded (256,)
    const float* __restrict__ w2p,            // padded (256,64)
    const float* __restrict__ b2,
    const float* __restrict__ wo,
    const float* __restrict__ bo,
    const float* __restrict__ us,
    const float* __restrict__ them,
    const int*   __restrict__ w_idx,
    const int*   __restrict__ b_idx,
    const int*   __restrict__ pcnt,
    float* __restrict__ out,
    int B)
{
    // 512 threads = 8 waves; 16 batch rows per block, 2 rows per wave.
    __shared__ unsigned short A_lds[16 * 280];          // 8960 B
    __shared__ float l1c[8 * 16 * 36];                  // 18432 B
    __shared__ float psq_lds[16];
    __shared__ int   bkt_lds[16];

    const int tid  = threadIdx.x;
    const int lane = tid & 63;
    const int w    = tid >> 6;            // wave 0..7

    // ---------- phase 1: gather (2 rows per wave), scalar-indexed saddr loads ----------
    for (int rr = 0; rr < 2; ++rr) {
        const int m = w * 2 + rr;
        const int grow = __builtin_amdgcn_readfirstlane(blockIdx.x * 16 + m); // B%16==0

        const float usv = us[grow];
        const float thv = them[grow];
        int bucket = (pcnt[grow] - 1) >> 2;
        bucket = bucket > 7 ? 7 : bucket;
        bucket = __builtin_amdgcn_readfirstlane(bucket);

        const int* wrow = w_idx + grow * 32;   // wave-uniform pointers -> s_load
        const int* brow = b_idx + grow * 32;

        // psqt: per-lane gather (lanes 0..31 w side, 32..63 b side)
        const int kk = lane & 31;
        const int pidx = (lane < 32) ? wrow[kk] : brow[kk];
        float ps = psqt[pidx * 8 + bucket];
        ps += __shfl_xor(ps, 16);
        ps += __shfl_xor(ps, 8);
        ps += __shfl_xor(ps, 4);
        ps += __shfl_xor(ps, 2);
        ps += __shfl_xor(ps, 1);
        const float psq_w = __shfl(ps, 0);
        const float psq_b = __shfl(ps, 32);

        // Gather: every feature row = one wave-wide 256B load, base in SGPRs.
        unsigned aw0 = 0, aw1 = 0, ab0 = 0, ab1 = 0;
        const unsigned M = 0x00FF00FFu;
#pragma unroll
        for (int kb = 0; kb < 32; kb += 16) {
            unsigned vw[16], vb[16];
#pragma unroll
            for (int k2 = 0; k2 < 16; ++k2) {
                const int iw = __builtin_amdgcn_readfirstlane(wrow[kb + k2]);
                vw[k2] = emb8[(size_t)iw * 64 + lane];
            }
#pragma unroll
            for (int k2 = 0; k2 < 16; ++k2) {
                const int ib = __builtin_amdgcn_readfirstlane(brow[kb + k2]);
                vb[k2] = emb8[(size_t)ib * 64 + lane];
            }
#pragma unroll
            for (int k2 = 0; k2 < 16; ++k2) {
                aw0 += vw[k2] & M; aw1 += (vw[k2] >> 8) & M;
                ab0 += vb[k2] & M; ab1 += (vb[k2] >> 8) & M;
            }
        }
        float4 aw, ab;
        aw.x = ((int)(aw0 & 0xffffu) - 4096) * INVQS;
        aw.y = ((int)(aw1 & 0xffffu) - 4096) * INVQS;
        aw.z = ((int)(aw0 >> 16)     - 4096) * INVQS;
        aw.w = ((int)(aw1 >> 16)     - 4096) * INVQS;
        ab.x = ((int)(ab0 & 0xffffu) - 4096) * INVQS;
        ab.y = ((int)(ab1 & 0xffffu) - 4096) * INVQS;
        ab.z = ((int)(ab0 >> 16)     - 4096) * INVQS;
        ab.w = ((int)(ab1 >> 16)     - 4096) * INVQS;

        float4 p, q;
        p.x = clamp01(usv * aw.x + thv * ab.x);
        p.y = clamp01(usv * aw.y + thv * ab.y);
        p.z = clamp01(usv * aw.z + thv * ab.z);
        p.w = clamp01(usv * aw.w + thv * ab.w);
        q.x = clamp01(usv * ab.x + thv * aw.x);
        q.y = clamp01(usv * ab.y + thv * aw.y);
        q.z = clamp01(usv * ab.z + thv * aw.z);
        q.w = clamp01(usv * ab.w + thv * aw.w);

        float4 po, qo;
        po.x = __shfl_xor(p.x, 32); po.y = __shfl_xor(p.y, 32);
        po.z = __shfl_xor(p.z, 32); po.w = __shfl_xor(p.w, 32);
        qo.x = __shfl_xor(q.x, 32); qo.y = __shfl_xor(q.y, 32);
        qo.z = __shfl_xor(q.z, 32); qo.w = __shfl_xor(q.w, 32);
        const float c127 = 127.f / 128.f;
        float4 l0f;
        if (lane < 32) {
            l0f.x = p.x * po.x * c127; l0f.y = p.y * po.y * c127;
            l0f.z = p.z * po.z * c127; l0f.w = p.w * po.w * c127;
        } else {
            l0f.x = q.x * qo.x * c127; l0f.y = q.y * qo.y * c127;
            l0f.z = q.z * qo.z * c127; l0f.w = q.w * qo.w * c127;
        }

        const unsigned lo  = (unsigned)f2bf(l0f.x) | ((unsigned)f2bf(l0f.y) << 16);
        const unsigned hi2 = (unsigned)f2bf(l0f.z) | ((unsigned)f2bf(l0f.w) << 16);
        *((unsigned long long*)&A_lds[m * 280 + lane * 4]) =
            ((unsigned long long)hi2 << 32) | (unsigned long long)lo;
        if (lane == 0) {
            psq_lds[m] = (psq_w - psq_b) * (usv - 0.5f);
            bkt_lds[m] = bucket;
        }
    }
    __syncthreads();

    // ---------- phase 2: l1 via MFMA, wave w handles bucket w ----------
    {
        const int col = lane & 15;
        const int hi  = lane >> 4;
        const int bkt = w;
        f32x4 acc[2];
        acc[0] = (f32x4){0.f, 0.f, 0.f, 0.f};
        acc[1] = (f32x4){0.f, 0.f, 0.f, 0.f};

#pragma unroll
        for (int s = 0; s < 8; ++s) {
            const short8 a = *((const short8*)&A_lds[col * 280 + s * 32 + hi * 8]);
#pragma unroll
            for (int nt = 0; nt < 2; ++nt) {
                const short8 bf = *((const short8*)&w1b[(((bkt * 8 + s) * 2 + nt) * 64 + lane) * 8]);
                acc[nt] = __builtin_amdgcn_mfma_f32_16x16x32_bf16(a, bf, acc[nt], 0, 0, 0);
            }
        }
#pragma unroll
        for (int nt = 0; nt < 2; ++nt) {
            const float bias = b1c[bkt * 32 + nt * 16 + col];
#pragma unroll
            for (int reg = 0; reg < 4; ++reg) {
                const int mr = hi * 4 + reg;
                l1c[(bkt * 16 + mr) * 36 + nt * 16 + col] = acc[nt][reg] + bias;
            }
        }
    }
    __syncthreads();

    // ---------- phase 3: l2 + l3, thread = (row, output-pair), tid < 256 ----------
    if (tid < 256) {
        const int row = tid >> 4;
        const int jj  = tid & 15;
        const int bkt = bkt_lds[row];
        const float4* crow = (const float4*)&l1c[(bkt * 16 + row) * 36];
        float4 c4[8];
#pragma unroll
        for (int b5 = 0; b5 < 8; ++b5) c4[b5] = crow[b5];

        const float4* wr0 = (const float4*)&w2p[(bkt * 32 + jj) * 64];
        const float4* wr1 = (const float4*)&w2p[(bkt * 32 + jj + 16) * 64];
        float acc0 = 0.f, acc1 = 0.f;
        const float kq = 255.f / 256.f;
#pragma unroll
        for (int b5 = 0; b5 < 8; ++b5) {
            const float4 cv = c4[b5];
            float4 sq, ln;
            sq.x = clamp01(cv.x * cv.x * kq); ln.x = clamp01(cv.x);
            sq.y = clamp01(cv.y * cv.y * kq); ln.y = clamp01(cv.y);
            sq.z = clamp01(cv.z * cv.z * kq); ln.z = clamp01(cv.z);
            sq.w = clamp01(cv.w * cv.w * kq); ln.w = clamp01(cv.w);
            const float4 ws0 = wr0[b5], wl0 = wr0[8 + b5];
            const float4 ws1 = wr1[b5], wl1 = wr1[8 + b5];
            acc0 += sq.x * ws0.x + sq.y * ws0.y + sq.z * ws0.z + sq.w * ws0.w;
            acc0 += ln.x * wl0.x + ln.y * wl0.y + ln.z * wl0.z + ln.w * wl0.w;
            acc1 += sq.x * ws1.x + sq.y * ws1.y + sq.z * ws1.z + sq.w * ws1.w;
            acc1 += ln.x * wl1.x + ln.y * wl1.y + ln.z * wl1.z + ln.w * wl1.w;
        }
        const float t0 = clamp01(acc0 + b2[bkt * 32 + jj])      * wo[bkt * 32 + jj];
        const float t1 = clamp01(acc1 + b2[bkt * 32 + jj + 16]) * wo[bkt * 32 + jj + 16];
        float t = t0 + t1;
        t += __shfl_xor(t, 8);
        t += __shfl_xor(t, 4);
        t += __shfl_xor(t, 2);
        t += __shfl_xor(t, 1);
        if (jj == 0) {
            out[blockIdx.x * 16 + row] = t + bo[bkt] + c4[7].w + psq_lds[row];
        }
    }
}

// ---------- fp32 fallback (self-contained, no workspace) ----------
__global__ __launch_bounds__(256) void nnue_fwd_f32(
    const float* __restrict__ emb,
    const float* __restrict__ w1e, const float* __restrict__ fw1,
    const float* __restrict__ b1e, const float* __restrict__ fb1,
    const float* __restrict__ w2,  const float* __restrict__ b2,
    const float* __restrict__ wo,  const float* __restrict__ bo,
    const float* __restrict__ us,  const float* __restrict__ them,
    const int* __restrict__ w_idx, const int* __restrict__ b_idx,
    const int* __restrict__ pcnt,  float* __restrict__ out, int B)
{
    const int lane = threadIdx.x & 63;
    const int row  = blockIdx.x * 4 + (threadIdx.x >> 6);
    if (row >= B) return;
    const float usv = us[row];
    const float thv = them[row];
    int bucket = (pcnt[row] - 1) >> 2;
    bucket = bucket > 7 ? 7 : bucket;
    bucket = __builtin_amdgcn_readfirstlane(bucket);
    const int kk = lane & 31;
    const int myidx = (lane < 32) ? w_idx[row * 32 + kk] : b_idx[row * 32 + kk];
    float ps = emb[(size_t)myidx * EMBD + 256 + bucket];
    ps += __shfl_xor(ps, 16); ps += __shfl_xor(ps, 8);
    ps += __shfl_xor(ps, 4);  ps += __shfl_xor(ps, 2); ps += __shfl_xor(ps, 1);
    const float psq_w = __shfl(ps, 0);
    const float psq_b = __shfl(ps, 32);
    float4 aw = make_float4(0,0,0,0), ab = make_float4(0,0,0,0);
#pragma unroll
    for (int k = 0; k < 32; ++k) {
        const int iw = __shfl(myidx, k);
        const int ib = __shfl(myidx, 32 + k);
        const float4 vw = *((const float4*)(emb + (size_t)iw * EMBD) + lane);
        const float4 vb = *((const float4*)(emb + (size_t)ib * EMBD) + lane);
        aw.x += vw.x; aw.y += vw.y; aw.z += vw.z; aw.w += vw.w;
        ab.x += vb.x; ab.y += vb.y; ab.z += vb.z; ab.w += vb.w;
    }
    float4 p, q;
    p.x = clamp01(usv*aw.x + thv*ab.x); p.y = clamp01(usv*aw.y + thv*ab.y);
    p.z = clamp01(usv*aw.z + thv*ab.z); p.w = clamp01(usv*aw.w + thv*ab.w);
    q.x = clamp01(usv*ab.x + thv*aw.x); q.y = clamp01(usv*ab.y + thv*aw.y);
    q.z = clamp01(usv*ab.z + thv*aw.z); q.w = clamp01(usv*ab.w + thv*aw.w);
    float4 po, qo;
    po.x = __shfl_xor(p.x,32); po.y = __shfl_xor(p.y,32);
    po.z = __shfl_xor(p.z,32); po.w = __shfl_xor(p.w,32);
    qo.x = __shfl_xor(q.x,32); qo.y = __shfl_xor(q.y,32);
    qo.z = __shfl_xor(q.z,32); qo.w = __shfl_xor(q.w,32);
    const float c127 = 127.f/128.f;
    float4 l0f;
    if (lane < 32) { l0f.x=p.x*po.x*c127; l0f.y=p.y*po.y*c127; l0f.z=p.z*po.z*c127; l0f.w=p.w*po.w*c127; }
    else           { l0f.x=q.x*qo.x*c127; l0f.y=q.y*qo.y*c127; l0f.z=q.z*qo.z*c127; l0f.w=q.w*qo.w*c127; }
    float part[32];
    const float4* w1p = (const float4*)(w1e + (size_t)bucket * 8192);
    const float4* f1p = (const float4*)fw1;
#pragma unroll
    for (int j = 0; j < 32; ++j) {
        float4 wv = w1p[j*64 + lane];
        float4 fv = f1p[j*64 + lane];
        wv.x+=fv.x; wv.y+=fv.y; wv.z+=fv.z; wv.w+=fv.w;
        part[j] = l0f.x*wv.x + l0f.y*wv.y + l0f.z*wv.z + l0f.w*wv.w;
    }
#pragma unroll
    for (int j = 0; j < 32; ++j) {
        float v = part[j];
        v += __shfl_xor(v,32); v += __shfl_xor(v,16); v += __shfl_xor(v,8);
        v += __shfl_xor(v,4);  v += __shfl_xor(v,2);  v += __shfl_xor(v,1);
        part[j] = v + b1e[bucket*32 + j] + fb1[j];
    }
    const float l1x_out = part[31];
    float acc2 = 0.f;
    if (lane < 32) {
        const float* w2r = w2 + (size_t)(bucket*32 + lane) * 62;
#pragma unroll
        for (int i = 0; i < 31; ++i) {
            const float a = part[i];
            acc2 += clamp01(a*a*(255.f/256.f)) * w2r[i];
            acc2 += clamp01(a) * w2r[31+i];
        }
        acc2 += b2[bucket*32 + lane];
        acc2 = clamp01(acc2) * wo[bucket*32 + lane];
    }
    acc2 += __shfl_xor(acc2,16); acc2 += __shfl_xor(acc2,8);
    acc2 += __shfl_xor(acc2,4);  acc2 += __shfl_xor(acc2,2); acc2 += __shfl_xor(acc2,1);
    if (lane == 0)
        out[row] = acc2 + bo[bucket] + l1x_out + (psq_w - psq_b) * (usv - 0.5f);
}

extern "C" void kernel_launch(void* const* d_in, const int* in_sizes, int n_in,
                              void* d_out, int out_size, void* d_ws, size_t ws_size,
                              hipStream_t stream) {
    const float* emb  = (const float*)d_in[0];
    const float* w1   = (const float*)d_in[1];
    const float* b1   = (const float*)d_in[2];
    const float* fw1  = (const float*)d_in[3];
    const float* fb1  = (const float*)d_in[4];
    const float* w2   = (const float*)d_in[5];
    const float* b2   = (const float*)d_in[6];
    const float* wo   = (const float*)d_in[7];
    const float* bo   = (const float*)d_in[8];
    const float* us   = (const float*)d_in[9];
    const float* them = (const float*)d_in[10];
    const int*   wi   = (const int*)d_in[11];
    const int*   bi   = (const int*)d_in[12];
    const int*   pc   = (const int*)d_in[13];
    float* out = (float*)d_out;

    const int B = in_sizes[9];               // 16384

    const size_t emb8_bytes = (size_t)NROWS * 256;   // 5,243,136
    const size_t psqt_bytes = (size_t)NROWS * 8 * 4; //   655,392
    const size_t w1b_bytes  = 65536 * 2;
    const size_t b1c_bytes  = 256 * 4;
    const size_t w2p_bytes  = 16384 * 4;
    const size_t need = emb8_bytes + psqt_bytes + w1b_bytes + b1c_bytes + w2p_bytes;

    if (ws_size >= need && (B % 16) == 0) {
        char* p = (char*)d_ws;
        unsigned int*   emb8 = (unsigned int*)p;     p += emb8_bytes;
        float*          psqt = (float*)p;            p += psqt_bytes;
        unsigned short* w1b  = (unsigned short*)p;   p += w1b_bytes;
        float*          b1c  = (float*)p;            p += b1c_bytes;
        float*          w2p  = (float*)p;

        prep_all<<<NR4 + 256, 256, 0, stream>>>(emb, emb8, psqt,
                                                w1, fw1, b1, fb1, w2, w1b, b1c, w2p);
        nnue_fwd_mfma<<<B / 16, 512, 0, stream>>>(emb8, psqt, w1b, b1c, w2p,
                                                  b2, wo, bo, us, them, wi, bi, pc, out, B);
    } else {
        nnue_fwd_f32<<<(B + 3) / 4, 256, 0, stream>>>(emb, w1, fw1, b1, fb1,
                                                      w2, b2, wo, bo, us, them, wi, bi, pc, out, B);
    }
}